// Round 11
// baseline (118.778 us; speedup 1.0000x reference)
//
#include <hip/hip_runtime.h>

#define DM 2048
#define NG 64
#define EPSV 1e-8f
#define ROWF 2052            // row stride in floats (8192 B + 16 B pad)

typedef __attribute__((ext_vector_type(4))) float f32x4;
typedef __attribute__((ext_vector_type(4))) int i32x4;
typedef __attribute__((ext_vector_type(4))) unsigned int u32x4;
typedef __attribute__((ext_vector_type(8))) short bf16x8;

__device__ __forceinline__ void stage16(const float* gsrc, float* ldst) {
  __builtin_amdgcn_global_load_lds(
      (const __attribute__((address_space(1))) unsigned int*)gsrc,
      (__attribute__((address_space(3))) unsigned int*)ldst, 16, 0, 0);
}

// split 8 fp32 into hi (truncate) / lo (rne residual) bf16.
__device__ __forceinline__ void split8(f32x4 x0, f32x4 x1, bf16x8& ah, bf16x8& al) {
  u32x4 u0 = __builtin_bit_cast(u32x4, x0);
  u32x4 u1 = __builtin_bit_cast(u32x4, x1);
  i32x4 hi;
  hi.x = (int)((u0.x >> 16) | (u0.y & 0xffff0000u));
  hi.y = (int)((u0.z >> 16) | (u0.w & 0xffff0000u));
  hi.z = (int)((u1.x >> 16) | (u1.y & 0xffff0000u));
  hi.w = (int)((u1.z >> 16) | (u1.w & 0xffff0000u));
  u32x4 m0 = u0 & 0xffff0000u;
  u32x4 m1 = u1 & 0xffff0000u;
  f32x4 r0 = x0 - __builtin_bit_cast(f32x4, m0);
  f32x4 r1 = x1 - __builtin_bit_cast(f32x4, m1);
  int lo0, lo1, lo2, lo3;
  asm("v_cvt_pk_bf16_f32 %0, %1, %2" : "=v"(lo0) : "v"(r0.x), "v"(r0.y));
  asm("v_cvt_pk_bf16_f32 %0, %1, %2" : "=v"(lo1) : "v"(r0.z), "v"(r0.w));
  asm("v_cvt_pk_bf16_f32 %0, %1, %2" : "=v"(lo2) : "v"(r1.x), "v"(r1.y));
  asm("v_cvt_pk_bf16_f32 %0, %1, %2" : "=v"(lo3) : "v"(r1.z), "v"(r1.w));
  i32x4 lo; lo.x = lo0; lo.y = lo1; lo.z = lo2; lo.w = lo3;
  ah = __builtin_bit_cast(bf16x8, hi);
  al = __builtin_bit_cast(bf16x8, lo);
}

// ---------------- Kernel 0: W split, wave-linear fragment layout ----------------
// unit index tg = S*256 + nt*64 + q4*16 + l15 holds W[nt*16+l15][S*32+q4*8 .. +8].
// A wave reading (q4=lane>>4, l15=lane&15) at byte tg*16 = S*4096 + nt*1024 + lane*16
// is a 1 KB contiguous run per (S, nt).
__global__ __launch_bounds__(256) void moe_prep(
    const float* __restrict__ W, unsigned short* __restrict__ whp,
    unsigned short* __restrict__ wlp, int* __restrict__ counter)
{
  int tg = blockIdx.x * 256 + threadIdx.x;   // 0..16383
  if (tg == 0) *counter = 0;
  int l15 = tg & 15, q4 = (tg >> 4) & 3, nt = (tg >> 6) & 3, S = tg >> 8;
  int n = nt * 16 + l15;
  int k0 = S * 32 + q4 * 8;
  const float* src = &W[(size_t)n * DM + k0];
  f32x4 w0 = *(const f32x4*)&src[0];
  f32x4 w1 = *(const f32x4*)&src[4];
  bf16x8 ah, al;
  split8(w0, w1, ah, al);
  *(bf16x8*)&whp[(size_t)tg * 8] = ah;
  *(bf16x8*)&wlp[(size_t)tg * 8] = al;
}

// ---------------- Kernel 1: linear-stream GEMM + fused epilogue ----------------
// Block = 8 tokens x full K, 512 threads (8 waves). The block stages its 64 KB
// of x as ONE linear sweep (1 KB contiguous per wave-instruction, rows
// back-to-back) -> ~512 sequential DRAM streams chip-wide instead of ~16-65k
// scattered ones. Wave w computes k-slice [256w, 256w+256) for all 8 tokens
// (MFMA M=16 with rows 8-15 duplicated/discarded). LDS reduce + validated
// softmax/top-8/write + near-tie flag.
__global__ __launch_bounds__(512, 4) void moe_gemm(
    const float* __restrict__ x, const unsigned short* __restrict__ whp,
    const unsigned short* __restrict__ wlp, float* __restrict__ out,
    int* __restrict__ counter, int* __restrict__ flaglist, int mtok)
{
  __shared__ float sbuf[8 * ROWF];   // 65.7 KB; aliased as reduce buffer later

  const int tid  = threadIdx.x;
  const int lane = tid & 63;
  const int w    = tid >> 6;          // wave 0..7 = k-slice
  const int q4   = lane >> 4;
  const int l15  = lane & 15;
  const int tok0 = blockIdx.x * 8;

  // ---- one-shot linear stage: 64 chunks of 1 KB ----
  const float* xb = x + (size_t)tok0 * DM;
#pragma unroll
  for (int i = 0; i < 8; ++i) {
    int c = i * 8 + w;                // chunk 0..63
    int r = c >> 3, p = c & 7;
    stage16(xb + r * DM + p * 256 + lane * 4,
            &sbuf[r * ROWF + p * 256 + lane * 4]);
  }
  __syncthreads();                    // drains stage

  // ---- compute: wave w, k in [256w, 256w+256), 8 steps of 32 ----
  const float* arow = &sbuf[(l15 & 7) * ROWF + w * 256 + q4 * 8];
  const char* pbh = (const char*)whp + ((size_t)w * 8) * 4096 + lane * 16;
  const char* pbl = (const char*)wlp + ((size_t)w * 8) * 4096 + lane * 16;

  f32x4 acc0 = {}, acc1 = {}, acc2 = {}, acc3 = {};

#pragma unroll
  for (int s = 0; s < 8; ++s) {
    f32x4 x0 = *(const f32x4*)(arow + s * 32);
    f32x4 x1 = *(const f32x4*)(arow + s * 32 + 4);
    bf16x8 bh0 = *(const bf16x8*)(pbh + s * 4096);
    bf16x8 bh1 = *(const bf16x8*)(pbh + s * 4096 + 1024);
    bf16x8 bh2 = *(const bf16x8*)(pbh + s * 4096 + 2048);
    bf16x8 bh3 = *(const bf16x8*)(pbh + s * 4096 + 3072);
    bf16x8 bl0 = *(const bf16x8*)(pbl + s * 4096);
    bf16x8 bl1 = *(const bf16x8*)(pbl + s * 4096 + 1024);
    bf16x8 bl2 = *(const bf16x8*)(pbl + s * 4096 + 2048);
    bf16x8 bl3 = *(const bf16x8*)(pbl + s * 4096 + 3072);
    bf16x8 ah, al;
    split8(x0, x1, ah, al);
    acc0 = __builtin_amdgcn_mfma_f32_16x16x32_bf16(ah, bh0, acc0, 0, 0, 0);
    acc0 = __builtin_amdgcn_mfma_f32_16x16x32_bf16(al, bh0, acc0, 0, 0, 0);
    acc0 = __builtin_amdgcn_mfma_f32_16x16x32_bf16(ah, bl0, acc0, 0, 0, 0);
    acc1 = __builtin_amdgcn_mfma_f32_16x16x32_bf16(ah, bh1, acc1, 0, 0, 0);
    acc1 = __builtin_amdgcn_mfma_f32_16x16x32_bf16(al, bh1, acc1, 0, 0, 0);
    acc1 = __builtin_amdgcn_mfma_f32_16x16x32_bf16(ah, bl1, acc1, 0, 0, 0);
    acc2 = __builtin_amdgcn_mfma_f32_16x16x32_bf16(ah, bh2, acc2, 0, 0, 0);
    acc2 = __builtin_amdgcn_mfma_f32_16x16x32_bf16(al, bh2, acc2, 0, 0, 0);
    acc2 = __builtin_amdgcn_mfma_f32_16x16x32_bf16(ah, bl2, acc2, 0, 0, 0);
    acc3 = __builtin_amdgcn_mfma_f32_16x16x32_bf16(ah, bh3, acc3, 0, 0, 0);
    acc3 = __builtin_amdgcn_mfma_f32_16x16x32_bf16(al, bh3, acc3, 0, 0, 0);
    acc3 = __builtin_amdgcn_mfma_f32_16x16x32_bf16(ah, bl3, acc3, 0, 0, 0);
  }
  __syncthreads();                    // stage buffer dead -> alias as reduce

  // ---- per-wave partials -> LDS (rows 0-7 only; rotate-swizzled cols) ----
  if (q4 < 2) {
#pragma unroll
    for (int rg = 0; rg < 4; ++rg) {
      int m = q4 * 4 + rg;            // token row 0..7
      int rot = 8 * m;
      sbuf[w * 512 + m * 64 + (((0 * 16 + l15) + rot) & 63)] = acc0[rg];
      sbuf[w * 512 + m * 64 + (((1 * 16 + l15) + rot) & 63)] = acc1[rg];
      sbuf[w * 512 + m * 64 + (((2 * 16 + l15) + rot) & 63)] = acc2[rg];
      sbuf[w * 512 + m * 64 + (((3 * 16 + l15) + rot) & 63)] = acc3[rg];
    }
  }
  __syncthreads();

  // ---- epilogue: 8 tokens x 8 lanes (threads 0..63), validated math ----
  if (tid < 64) {
    const int t  = tid >> 3;
    const int li = tid & 7;
    float l[8];
#pragma unroll
    for (int j = 0; j < 8; ++j) {
      int c = ((li * 8 + j) + 8 * t) & 63;
      float v = 0.f;
#pragma unroll
      for (int ww = 0; ww < 8; ++ww) v += sbuf[ww * 512 + t * 64 + c];
      l[j] = v;
    }

    float m = l[0];
#pragma unroll
    for (int j = 1; j < 8; ++j) m = fmaxf(m, l[j]);
#pragma unroll
    for (int msk = 1; msk < 8; msk <<= 1) m = fmaxf(m, __shfl_xor(m, msk));

    float e[8];
    float sum = 0.f;
#pragma unroll
    for (int j = 0; j < 8; ++j) { e[j] = __expf(l[j] - m); sum += e[j]; }
#pragma unroll
    for (int msk = 1; msk < 8; msk <<= 1) sum += __shfl_xor(sum, msk);

    unsigned taken = 0;
    float esel = 0.f, e8 = 0.f, e9 = 0.f;
#pragma unroll 1
    for (int p = 0; p < 9; ++p) {
      float bv = -1.f;
      int bi = 127;
#pragma unroll
      for (int j = 0; j < 8; ++j) {
        bool avail = !((taken >> j) & 1u);
        float vv = e[j];
        int g = (li << 3) + j;
        bool better = avail && (vv > bv || (vv == bv && g < bi));
        bv = better ? vv : bv;
        bi = better ? g : bi;
      }
#pragma unroll
      for (int msk = 1; msk < 8; msk <<= 1) {
        float ov = __shfl_xor(bv, msk);
        int oi = __shfl_xor(bi, msk);
        bool better = (ov > bv) || (ov == bv && oi < bi);
        bv = better ? ov : bv;
        bi = better ? oi : bi;
      }
      if (p < 8) {
        esel += bv;
        if ((bi >> 3) == li) taken |= 1u << (bi & 7);
        if (p == 7) e8 = bv;
      } else {
        e9 = bv;
      }
    }

    if (li == 0 && e9 > e8 * 0.999f) {
      int ix = atomicAdd(counter, 1);
      flaglist[ix] = tok0 + t;
    }

    const float inv = 1.f / sum;
    const float rsc = 1.f / (esel + EPSV * sum);
    const size_t MN = (size_t)mtok * NG;
    const size_t base = (size_t)(tok0 + t) * NG + (li << 3);

    f32x4 r0, r1, m0, m1, s0, s1;
#pragma unroll
    for (int j = 0; j < 4; ++j) {
      float bitL = ((taken >> j) & 1u) ? 1.f : 0.f;
      float bitH = ((taken >> (j + 4)) & 1u) ? 1.f : 0.f;
      s0[j] = e[j] * inv;      s1[j] = e[j + 4] * inv;
      m0[j] = bitL;            m1[j] = bitH;
      r0[j] = bitL * e[j] * rsc;
      r1[j] = bitH * e[j + 4] * rsc;
    }
    *(f32x4*)&out[base]              = r0;
    *(f32x4*)&out[base + 4]          = r1;
    *(f32x4*)&out[MN + base]         = m0;
    *(f32x4*)&out[MN + base + 4]     = m1;
    *(f32x4*)&out[2 * MN + base]     = s0;
    *(f32x4*)&out[2 * MN + base + 4] = s1;
  }
}

// ---------------- Kernel 2: exact fp32 fixup, block-per-token ----------------
__global__ __launch_bounds__(256) void moe_fixup(
    const float* __restrict__ x, const float* __restrict__ W,
    float* __restrict__ out, const int* __restrict__ counter,
    const int* __restrict__ flaglist, int mtok)
{
  const int cnt = counter[0];
  const int g = threadIdx.x & 63;
  const int q = threadIdx.x >> 6;
  const size_t MN = (size_t)mtok * NG;
  __shared__ float part[4][64];

  for (int i = blockIdx.x; i < cnt; i += 256) {
    const int tok = flaglist[i];
    const float* xr = &x[(size_t)tok * DM + q * 512];
    const float* wr = &W[(size_t)g * DM + q * 512];
    f32x4 a = {0.f, 0.f, 0.f, 0.f};
#pragma unroll 8
    for (int k = 0; k < 512; k += 4)
      a += *(const f32x4*)&xr[k] * *(const f32x4*)&wr[k];
    part[q][g] = a.x + a.y + a.z + a.w;
    __syncthreads();

    if (q == 0) {
      float l = part[0][g] + part[1][g] + part[2][g] + part[3][g];

      float m = l;
#pragma unroll
      for (int msk = 1; msk < 64; msk <<= 1) m = fmaxf(m, __shfl_xor(m, msk));
      float e = __expf(l - m);
      float sum = e;
#pragma unroll
      for (int msk = 1; msk < 64; msk <<= 1) sum += __shfl_xor(sum, msk);

      bool sel = false;
#pragma unroll 1
      for (int p = 0; p < 8; ++p) {
        float bv = sel ? -3.4e38f : l;
        int bi = sel ? 1000 : g;
#pragma unroll
        for (int msk = 1; msk < 64; msk <<= 1) {
          float ov = __shfl_xor(bv, msk);
          int oi = __shfl_xor(bi, msk);
          bool better = (ov > bv) || (ov == bv && oi < bi);
          bv = better ? ov : bv;
          bi = better ? oi : bi;
        }
        if (bi == g) sel = true;
      }
      float esel = sel ? e : 0.f;
#pragma unroll
      for (int msk = 1; msk < 64; msk <<= 1) esel += __shfl_xor(esel, msk);

      const float inv = 1.f / sum;
      const float rsc = 1.f / (esel + EPSV * sum);
      const float bit = sel ? 1.f : 0.f;
      const size_t base = (size_t)tok * NG + g;
      out[base] = bit * e * rsc;
      out[MN + base] = bit;
      out[2 * MN + base] = e * inv;
    }
    __syncthreads();
  }
}

extern "C" void kernel_launch(void* const* d_in, const int* in_sizes, int n_in,
                              void* d_out, int out_size, void* d_ws, size_t ws_size,
                              hipStream_t stream) {
  const float* x = (const float*)d_in[0];
  const float* W = (const float*)d_in[1];
  float* out = (float*)d_out;
  const int mtok = in_sizes[0] / DM;          // 16384

  char* ws = (char*)d_ws;
  int* counter = (int*)ws;                               // @0
  int* flaglist = (int*)(ws + 4096);                     // 64 KB
  unsigned short* whp = (unsigned short*)(ws + 69632);   // 256 KB
  unsigned short* wlp = (unsigned short*)(ws + 331776);  // 256 KB

  hipLaunchKernelGGL(moe_prep, dim3(64), dim3(256), 0, stream, W, whp, wlp, counter);
  hipLaunchKernelGGL(moe_gemm, dim3(mtok / 8), dim3(512), 0, stream,
                     x, whp, wlp, out, counter, flaglist, mtok);
  hipLaunchKernelGGL(moe_fixup, dim3(256), dim3(256), 0, stream,
                     x, W, out, counter, flaglist, mtok);
}

// Round 12
// 72.322 us; speedup vs baseline: 1.6423x; 1.6423x over previous
//
#include <hip/hip_runtime.h>

#define DM 2048
#define NG 64
#define EPSV 1e-8f

typedef __attribute__((ext_vector_type(4))) float f32x4;
typedef __attribute__((ext_vector_type(16))) float f32x16;
typedef __attribute__((ext_vector_type(4))) int i32x4;
typedef __attribute__((ext_vector_type(4))) unsigned int u32x4;
typedef __attribute__((ext_vector_type(8))) short bf16x8;

__device__ __forceinline__ void stage16(const float* gsrc, float* ldst) {
  __builtin_amdgcn_global_load_lds(
      (const __attribute__((address_space(1))) unsigned int*)gsrc,
      (__attribute__((address_space(3))) unsigned int*)ldst, 16, 0, 0);
}

// split 8 fp32 into hi (truncate) / lo (rne residual) bf16.
__device__ __forceinline__ void split8(f32x4 x0, f32x4 x1, bf16x8& ah, bf16x8& al) {
  u32x4 u0 = __builtin_bit_cast(u32x4, x0);
  u32x4 u1 = __builtin_bit_cast(u32x4, x1);
  i32x4 hi;
  hi.x = (int)((u0.x >> 16) | (u0.y & 0xffff0000u));
  hi.y = (int)((u0.z >> 16) | (u0.w & 0xffff0000u));
  hi.z = (int)((u1.x >> 16) | (u1.y & 0xffff0000u));
  hi.w = (int)((u1.z >> 16) | (u1.w & 0xffff0000u));
  u32x4 m0 = u0 & 0xffff0000u;
  u32x4 m1 = u1 & 0xffff0000u;
  f32x4 r0 = x0 - __builtin_bit_cast(f32x4, m0);
  f32x4 r1 = x1 - __builtin_bit_cast(f32x4, m1);
  int lo0, lo1, lo2, lo3;
  asm("v_cvt_pk_bf16_f32 %0, %1, %2" : "=v"(lo0) : "v"(r0.x), "v"(r0.y));
  asm("v_cvt_pk_bf16_f32 %0, %1, %2" : "=v"(lo1) : "v"(r0.z), "v"(r0.w));
  asm("v_cvt_pk_bf16_f32 %0, %1, %2" : "=v"(lo2) : "v"(r1.x), "v"(r1.y));
  asm("v_cvt_pk_bf16_f32 %0, %1, %2" : "=v"(lo3) : "v"(r1.z), "v"(r1.w));
  i32x4 lo; lo.x = lo0; lo.y = lo1; lo.z = lo2; lo.w = lo3;
  ah = __builtin_bit_cast(bf16x8, hi);
  al = __builtin_bit_cast(bf16x8, lo);
}

// ---------------- Kernel 0: W split + counter reset ----------------
__global__ __launch_bounds__(256) void moe_prep(
    const float* __restrict__ W, unsigned short* __restrict__ whp,
    unsigned short* __restrict__ wlp, int* __restrict__ counter)
{
  int tg = blockIdx.x * 256 + threadIdx.x;   // 128*2*64 fragments
  if (tg == 0) *counter = 0;
  int S = tg >> 7, h = (tg >> 6) & 1, n = tg & 63;
  const float* src = &W[(size_t)n * DM + S * 16 + h * 8];
  f32x4 w0 = *(const f32x4*)&src[0];
  f32x4 w1 = *(const f32x4*)&src[4];
  bf16x8 ah, al;
  split8(w0, w1, ah, al);
  *(bf16x8*)&whp[(size_t)tg * 8] = ah;
  *(bf16x8*)&wlp[(size_t)tg * 8] = al;
}

// ---------------- Kernel 1: split-K=4 split-bf16 MFMA GEMM ----------------
// VERBATIM round-7 kernel except the blockIdx remap: the 4 k-slice blocks of a
// token-tile are now congruent mod 8 -> same XCD, near-simultaneous dispatch ->
// x tile fetched from L3 once, 3 L2 hits (kills 4x redundant fabric traffic).
__global__ __launch_bounds__(256, 4) void moe_gemm(
    const float* __restrict__ x, const unsigned short* __restrict__ whp,
    const unsigned short* __restrict__ wlp, float* __restrict__ out,
    float* __restrict__ pws, int mtok)
{
  __shared__ float xsr[2][64 * 64];   // 32 KB

  const int tid = threadIdx.x;
  const int lane = tid & 63;
  const int wid = tid >> 6;
  const int tm0 = (wid & 1) * 32;
  const int gn0 = (wid >> 1) * 32;

  // XCD-grouping remap: bid%8 = XCD (dispatch heuristic). Per XCD: 128 blocks
  // = 32 token-tiles x 4 slices, slices adjacent in dispatch order.
  const int bid = blockIdx.x;
  const int xcd = bid & 7;
  const int i8  = bid >> 3;           // 0..127
  const int sl  = i8 & 3;
  const int tb  = xcd * 32 + (i8 >> 2);
  const int tok0 = tb * 64;

  const int h = lane >> 5;
  const int ln = lane & 31;
  const int grp = gn0 + ln;
  const int w0 = sl * 8;              // first global 64k-window of this slice

  auto stage_window = [&](int c, int slot) {
    const float* xb = x + (size_t)tok0 * DM + (size_t)(w0 + c) * 64;
    float* ld = &xsr[slot][0];
#pragma unroll
    for (int i = 0; i < 4; ++i) {
      int idx = i * 256 + tid;
      int r = idx >> 4, q = idx & 15;
      int sq = q ^ (r & 15);
      stage16(xb + (size_t)r * DM + (sq << 2), ld + (idx << 2));
    }
  };

  bf16x8 Bh[4], Bl[4];                // single set, compile-time indices only
  f32x16 acc = {0.f,0.f,0.f,0.f,0.f,0.f,0.f,0.f,0.f,0.f,0.f,0.f,0.f,0.f,0.f,0.f};

#define LOADB(CC) do {                                                       \
    int w_ = w0 + (CC);                                                      \
    _Pragma("unroll")                                                        \
    for (int s = 0; s < 4; ++s) {                                            \
      size_t bidx = (((size_t)((w_ * 4 + s) * 2 + h) * 64) + grp) * 8;       \
      Bh[s] = *(const bf16x8*)&whp[bidx];                                    \
      Bl[s] = *(const bf16x8*)&wlp[bidx];                                    \
    }                                                                        \
  } while (0)

#define COMPUTE(CC) do {                                                     \
    const float* xrow_ = &xsr[(CC) & 1][(tm0 + ln) * 64];                    \
    const int rsw_ = ((tm0 + ln) & 15);                                      \
    _Pragma("unroll")                                                        \
    for (int s = 0; s < 4; ++s) {                                            \
      int qa = s * 4 + h * 2;                                                \
      f32x4 x0 = *(const f32x4*)&xrow_[((qa ^ rsw_) << 2)];                  \
      f32x4 x1 = *(const f32x4*)&xrow_[(((qa + 1) ^ rsw_) << 2)];            \
      bf16x8 ah, al;                                                         \
      split8(x0, x1, ah, al);                                                \
      acc = __builtin_amdgcn_mfma_f32_32x32x16_bf16(ah, Bh[s], acc, 0, 0, 0); \
      acc = __builtin_amdgcn_mfma_f32_32x32x16_bf16(al, Bh[s], acc, 0, 0, 0); \
      acc = __builtin_amdgcn_mfma_f32_32x32x16_bf16(ah, Bl[s], acc, 0, 0, 0); \
    }                                                                        \
  } while (0)

  stage_window(0, 0);
  __syncthreads();

#pragma unroll 1
  for (int c = 0; c < 8; ++c) {
    LOADB(c);                                   // B regs for this window first
    __builtin_amdgcn_sched_barrier(0);          // pin: stages issue AFTER B loads
    if (c < 7) stage_window(c + 1, (c + 1) & 1);
    COMPUTE(c);                                 // auto vmcnt(16): B ready, x streaming
    __syncthreads();
  }
#undef LOADB
#undef COMPUTE

  // partial logits -> slice buffer (C/D map: n = gn0+ln, m = tm0+(r&3)+8*(r>>2)+4*h)
  float* ps = (sl < 3) ? (out + (size_t)sl * mtok * NG) : pws;
#pragma unroll
  for (int r = 0; r < 16; ++r) {
    int m = tm0 + (r & 3) + 8 * (r >> 2) + 4 * h;
    ps[(size_t)(tok0 + m) * NG + grp] = acc[r];
  }
}

// ---------------- Kernel 2: reduce + softmax + top-8 + flag + write ----------------
__global__ __launch_bounds__(256) void moe_finish(
    float* __restrict__ out, const float* __restrict__ pws,
    int* __restrict__ counter, int* __restrict__ flaglist, int mtok)
{
  const int tid = threadIdx.x;
  const int t   = blockIdx.x * 32 + (tid >> 3);
  const int l8  = tid & 7;
  const size_t MN = (size_t)mtok * NG;
  const size_t base = (size_t)t * NG + (l8 << 3);

  f32x4 a0 = {0.f, 0.f, 0.f, 0.f}, a1 = {0.f, 0.f, 0.f, 0.f};
#pragma unroll
  for (int s = 0; s < 4; ++s) {
    const float* p = (s < 3) ? (out + (size_t)s * MN) : pws;
    a0 += *(const f32x4*)&p[base];
    a1 += *(const f32x4*)&p[base + 4];
  }

  float l[8];
#pragma unroll
  for (int j = 0; j < 4; ++j) { l[j] = a0[j]; l[j + 4] = a1[j]; }

  float m = l[0];
#pragma unroll
  for (int j = 1; j < 8; ++j) m = fmaxf(m, l[j]);
#pragma unroll
  for (int msk = 1; msk < 8; msk <<= 1) m = fmaxf(m, __shfl_xor(m, msk));

  float e[8];
  float sum = 0.f;
#pragma unroll
  for (int j = 0; j < 8; ++j) { e[j] = __expf(l[j] - m); sum += e[j]; }
#pragma unroll
  for (int msk = 1; msk < 8; msk <<= 1) sum += __shfl_xor(sum, msk);

  unsigned taken = 0;
  float esel = 0.f, e8 = 0.f, e9 = 0.f;
#pragma unroll 1
  for (int p = 0; p < 9; ++p) {
    float bv = -1.f;
    int bi = 127;
#pragma unroll
    for (int j = 0; j < 8; ++j) {
      bool avail = !((taken >> j) & 1u);
      float vv = e[j];
      int g = (l8 << 3) + j;
      bool better = avail && (vv > bv || (vv == bv && g < bi));
      bv = better ? vv : bv;
      bi = better ? g : bi;
    }
#pragma unroll
    for (int msk = 1; msk < 8; msk <<= 1) {
      float ov = __shfl_xor(bv, msk);
      int oi = __shfl_xor(bi, msk);
      bool better = (ov > bv) || (ov == bv && oi < bi);
      bv = better ? ov : bv;
      bi = better ? oi : bi;
    }
    if (p < 8) {
      esel += bv;
      if ((bi >> 3) == l8) taken |= 1u << (bi & 7);
      if (p == 7) e8 = bv;
    } else {
      e9 = bv;
    }
  }

  // flag near-ties for exact recompute: l8-l9 < 1e-3  <=>  e9 > e8*exp(-1e-3)
  if (l8 == 0 && e9 > e8 * 0.999f) {
    int ix = atomicAdd(counter, 1);
    flaglist[ix] = t;
  }

  const float inv = 1.f / sum;
  const float rsc = 1.f / (esel + EPSV * sum);

  f32x4 r0, r1, m0, m1, s0, s1;
#pragma unroll
  for (int j = 0; j < 4; ++j) {
    float bitL = ((taken >> j) & 1u) ? 1.f : 0.f;
    float bitH = ((taken >> (j + 4)) & 1u) ? 1.f : 0.f;
    s0[j] = e[j] * inv;      s1[j] = e[j + 4] * inv;
    m0[j] = bitL;            m1[j] = bitH;
    r0[j] = bitL * e[j] * rsc;
    r1[j] = bitH * e[j + 4] * rsc;
  }
  *(f32x4*)&out[base]              = r0;
  *(f32x4*)&out[base + 4]          = r1;
  *(f32x4*)&out[MN + base]         = m0;
  *(f32x4*)&out[MN + base + 4]     = m1;
  *(f32x4*)&out[2 * MN + base]     = s0;
  *(f32x4*)&out[2 * MN + base + 4] = s1;
}

// ---------------- Kernel 3: exact fp32 fixup, block-per-token ----------------
__global__ __launch_bounds__(256) void moe_fixup(
    const float* __restrict__ x, const float* __restrict__ W,
    float* __restrict__ out, const int* __restrict__ counter,
    const int* __restrict__ flaglist, int mtok)
{
  const int cnt = counter[0];
  const int g = threadIdx.x & 63;
  const int q = threadIdx.x >> 6;
  const size_t MN = (size_t)mtok * NG;
  __shared__ float part[4][64];

  for (int i = blockIdx.x; i < cnt; i += 256) {
    const int tok = flaglist[i];
    const float* xr = &x[(size_t)tok * DM + q * 512];
    const float* wr = &W[(size_t)g * DM + q * 512];
    f32x4 a = {0.f, 0.f, 0.f, 0.f};
#pragma unroll 8
    for (int k = 0; k < 512; k += 4)
      a += *(const f32x4*)&xr[k] * *(const f32x4*)&wr[k];
    part[q][g] = a.x + a.y + a.z + a.w;
    __syncthreads();

    if (q == 0) {
      float l = part[0][g] + part[1][g] + part[2][g] + part[3][g];

      float m = l;
#pragma unroll
      for (int msk = 1; msk < 64; msk <<= 1) m = fmaxf(m, __shfl_xor(m, msk));
      float e = __expf(l - m);
      float sum = e;
#pragma unroll
      for (int msk = 1; msk < 64; msk <<= 1) sum += __shfl_xor(sum, msk);

      bool sel = false;
#pragma unroll 1
      for (int p = 0; p < 8; ++p) {
        float bv = sel ? -3.4e38f : l;
        int bi = sel ? 1000 : g;
#pragma unroll
        for (int msk = 1; msk < 64; msk <<= 1) {
          float ov = __shfl_xor(bv, msk);
          int oi = __shfl_xor(bi, msk);
          bool better = (ov > bv) || (ov == bv && oi < bi);
          bv = better ? ov : bv;
          bi = better ? oi : bi;
        }
        if (bi == g) sel = true;
      }
      float esel = sel ? e : 0.f;
#pragma unroll
      for (int msk = 1; msk < 64; msk <<= 1) esel += __shfl_xor(esel, msk);

      const float inv = 1.f / sum;
      const float rsc = 1.f / (esel + EPSV * sum);
      const float bit = sel ? 1.f : 0.f;
      const size_t base = (size_t)tok * NG + g;
      out[base] = bit * e * rsc;
      out[MN + base] = bit;
      out[2 * MN + base] = e * inv;
    }
    __syncthreads();
  }
}

extern "C" void kernel_launch(void* const* d_in, const int* in_sizes, int n_in,
                              void* d_out, int out_size, void* d_ws, size_t ws_size,
                              hipStream_t stream) {
  const float* x = (const float*)d_in[0];
  const float* W = (const float*)d_in[1];
  float* out = (float*)d_out;
  const int mtok = in_sizes[0] / DM;          // 16384

  char* ws = (char*)d_ws;
  int* counter = (int*)ws;                               // @0
  int* flaglist = (int*)(ws + 4096);                     // 64 KB
  unsigned short* whp = (unsigned short*)(ws + 69632);   // 256 KB
  unsigned short* wlp = (unsigned short*)(ws + 331776);  // 256 KB
  float* pws = (float*)(ws + (1u << 20));                // 4 MB (k-slice 3 partials)

  hipLaunchKernelGGL(moe_prep, dim3(64), dim3(256), 0, stream, W, whp, wlp, counter);
  hipLaunchKernelGGL(moe_gemm, dim3((mtok / 64) * 4), dim3(256), 0, stream,
                     x, whp, wlp, out, pws, mtok);
  hipLaunchKernelGGL(moe_finish, dim3(mtok / 32), dim3(256), 0, stream,
                     out, pws, counter, flaglist, mtok);
  hipLaunchKernelGGL(moe_fixup, dim3(256), dim3(256), 0, stream,
                     x, W, out, counter, flaglist, mtok);
}